// Round 2
// baseline (1179.045 us; speedup 1.0000x reference)
//
#include <hip/hip_runtime.h>
#include <math.h>

// Problem constants
#define Bn 2
#define Sn 2048
#define Dn 1024
#define Hn 16
#define HDn 64
#define MLPn 4096
#define Mn 4096  // Bn*Sn tokens
#define NCHUNK 8 // Sn/256

typedef float f4 __attribute__((ext_vector_type(4)));
typedef short bfrag __attribute__((ext_vector_type(8)));     // 8 bf16 for MFMA
typedef unsigned int u32x2 __attribute__((ext_vector_type(2)));
typedef unsigned int u32x4 __attribute__((ext_vector_type(4)));
typedef unsigned short u16x4 __attribute__((ext_vector_type(4)));

__device__ __forceinline__ unsigned short f2bf(float f) {
  unsigned u = __float_as_uint(f);
  u += 0x7fffu + ((u >> 16) & 1u);   // RNE
  return (unsigned short)(u >> 16);
}
__device__ __forceinline__ float bf2f(unsigned short u) {
  return __uint_as_float(((unsigned)u) << 16);
}
__device__ __forceinline__ f4 load4bf(const unsigned short* p) {
  u32x2 u = *(const u32x2*)p;
  f4 r;
  r[0] = __uint_as_float(u[0] << 16);
  r[1] = __uint_as_float(u[0] & 0xffff0000u);
  r[2] = __uint_as_float(u[1] << 16);
  r[3] = __uint_as_float(u[1] & 0xffff0000u);
  return r;
}
// 8 bf16 (16B, coalescing sweet spot) -> two f4
__device__ __forceinline__ void load8bf(const unsigned short* p, f4* a, f4* b) {
  u32x4 u = *(const u32x4*)p;
  (*a)[0] = __uint_as_float(u[0] << 16);
  (*a)[1] = __uint_as_float(u[0] & 0xffff0000u);
  (*a)[2] = __uint_as_float(u[1] << 16);
  (*a)[3] = __uint_as_float(u[1] & 0xffff0000u);
  (*b)[0] = __uint_as_float(u[2] << 16);
  (*b)[1] = __uint_as_float(u[2] & 0xffff0000u);
  (*b)[2] = __uint_as_float(u[3] << 16);
  (*b)[3] = __uint_as_float(u[3] & 0xffff0000u);
}
__device__ __forceinline__ void store4bf(unsigned short* p, f4 v) {
  u16x4 o;
  o[0] = f2bf(v[0]); o[1] = f2bf(v[1]); o[2] = f2bf(v[2]); o[3] = f2bf(v[3]);
  *(u16x4*)p = o;
}

#define GLOAD16(gp, lp) __builtin_amdgcn_global_load_lds( \
    (const __attribute__((address_space(1))) void*)(gp),  \
    (__attribute__((address_space(3))) void*)(lp), 16, 0, 0)

// ---------------------------------------------------------------------------
// Weight transpose + fp32->bf16: in [K][N] fp32  ->  out [N][K] bf16
// ---------------------------------------------------------------------------
__global__ void transpose_to_bf16(const float* __restrict__ in,
                                  unsigned short* __restrict__ out,
                                  int K, int N) {
  __shared__ float tile[32][33];
  const int n0 = blockIdx.x * 32;
  const int k0 = blockIdx.y * 32;
  const int tx = threadIdx.x, ty = threadIdx.y;  // (32,8)
  #pragma unroll
  for (int i = 0; i < 32; i += 8)
    tile[ty + i][tx] = in[(size_t)(k0 + ty + i) * N + n0 + tx];
  __syncthreads();
  #pragma unroll
  for (int i = 0; i < 32; i += 8)
    out[(size_t)(n0 + ty + i) * K + k0 + tx] = f2bf(tile[tx][ty + i]);
}

// ---------------------------------------------------------------------------
// LayerNorm over D=1024, fp32 in -> bf16 out. One block per row.
// ---------------------------------------------------------------------------
__global__ __launch_bounds__(256)
void ln_k(const float* __restrict__ x, const float* __restrict__ g,
          const float* __restrict__ bta, unsigned short* __restrict__ out) {
  const int row = blockIdx.x;
  const int tid = threadIdx.x;
  const float* xr = x + (size_t)row * Dn;
  f4 v = ((const f4*)xr)[tid];
  float s  = v[0] + v[1] + v[2] + v[3];
  float s2 = v[0]*v[0] + v[1]*v[1] + v[2]*v[2] + v[3]*v[3];
  #pragma unroll
  for (int off = 32; off > 0; off >>= 1) {
    s  += __shfl_down(s, off);
    s2 += __shfl_down(s2, off);
  }
  __shared__ float red[8];
  if ((tid & 63) == 0) { red[tid >> 6] = s; red[4 + (tid >> 6)] = s2; }
  __syncthreads();
  const float mean = (red[0] + red[1] + red[2] + red[3]) * (1.f / Dn);
  const float var  = (red[4] + red[5] + red[6] + red[7]) * (1.f / Dn) - mean * mean;
  const float inv  = rsqrtf(var + 1e-5f);
  f4 gv = ((const f4*)g)[tid];
  f4 bv = ((const f4*)bta)[tid];
  u16x4 o;
  o[0] = f2bf((v[0] - mean) * inv * gv[0] + bv[0]);
  o[1] = f2bf((v[1] - mean) * inv * gv[1] + bv[1]);
  o[2] = f2bf((v[2] - mean) * inv * gv[2] + bv[2]);
  o[3] = f2bf((v[3] - mean) * inv * gv[3] + bv[3]);
  ((u16x4*)(out + (size_t)row * Dn))[tid] = o;
}

// ---------------------------------------------------------------------------
// bf16 MFMA GEMM, m97 structure: C[M][N] = A[M][K] * Bt[N][K]^T (+ epilogue)
// 128x128 tile, BK=32, 4 waves (2x2), 4x4 16x16 fragments per wave.
// MODE 0: bf16 = elu(acc+b)+1, scatter head-major -> q (outb) / k (outb2)
// MODE 1: bf16 = acc+b, scatter head-major -> v (outb)
// MODE 2: f32  = acc+b+lambd*res           (attn_out + skip -> xmid)
// MODE 3: bf16 = gelu_tanh(acc+b)          (mlp hidden)
// MODE 4: f32  = acc+b+res                 (final)
// ---------------------------------------------------------------------------
template<int MODE>
__global__ __launch_bounds__(256)
void gemm_bt(const unsigned short* __restrict__ A,
             const unsigned short* __restrict__ Bt,
             int Mdim, int Ndim, int Kdim,
             const float* __restrict__ bias,
             const float* __restrict__ res,
             const float* __restrict__ lambd,
             float* __restrict__ outf,
             unsigned short* __restrict__ outb,
             unsigned short* __restrict__ outb2) {
  __shared__ unsigned short As[128 * 32];
  __shared__ unsigned short Bs[128 * 32];
  const int tid  = threadIdx.x;
  const int lane = tid & 63;
  const int wid  = tid >> 6;
  const int wr   = wid >> 1, wc = wid & 1;
  const int bm = blockIdx.x, bn = blockIdx.y;

  f4 acc[4][4] = {};

  const int lrow = lane >> 2;        // 0..15
  const int lcol = (lane & 3) * 8;   // element col within BK
  const unsigned short* Ag = A + (size_t)(bm * 128 + lrow) * Kdim + lcol;
  const unsigned short* Bg = Bt + (size_t)(bn * 128 + lrow) * Kdim + lcol;

  const int arow = wr * 64 + (lane & 15);
  const int brow = wc * 64 + (lane & 15);
  const int koff = (lane >> 4) * 8;

  for (int kt = 0; kt < Kdim; kt += 32) {
    __syncthreads();
    #pragma unroll
    for (int i = 0; i < 2; ++i) {
      const int rbase = (wid * 2 + i) * 16;
      GLOAD16(Ag + (size_t)rbase * Kdim + kt, As + rbase * 32);
      GLOAD16(Bg + (size_t)rbase * Kdim + kt, Bs + rbase * 32);
    }
    __syncthreads();

    bfrag af[4], bfr[4];
    #pragma unroll
    for (int mi = 0; mi < 4; ++mi)
      af[mi] = *(const bfrag*)(As + (arow + mi * 16) * 32 + koff);
    #pragma unroll
    for (int ni = 0; ni < 4; ++ni)
      bfr[ni] = *(const bfrag*)(Bs + (brow + ni * 16) * 32 + koff);
    #pragma unroll
    for (int mi = 0; mi < 4; ++mi)
      #pragma unroll
      for (int ni = 0; ni < 4; ++ni)
        acc[mi][ni] = __builtin_amdgcn_mfma_f32_16x16x32_bf16(
            af[mi], bfr[ni], acc[mi][ni], 0, 0, 0);
  }

  // epilogue
  const int r0 = bm * 128 + wr * 64 + ((lane >> 4) << 2);
  const int c0 = bn * 128 + wc * 64 + (lane & 15);
  const float lam = (MODE == 2) ? lambd[0] : 0.f;
  #pragma unroll
  for (int mi = 0; mi < 4; ++mi) {
    #pragma unroll
    for (int ni = 0; ni < 4; ++ni) {
      const int col = c0 + ni * 16;
      const float bcol = bias[col];
      #pragma unroll
      for (int r = 0; r < 4; ++r) {
        const int row = r0 + mi * 16 + r;
        const size_t idx = (size_t)row * Ndim + col;
        float v = acc[mi][ni][r] + bcol;
        if (MODE == 0) {
          v = (v > 0.f) ? (v + 1.f) : __expf(v);   // elu+1
          const int part = col >> 10, hh = (col >> 6) & 15, dd = col & 63;
          const int bb = row >> 11, ss = row & 2047;
          unsigned short* dst = part ? outb2 : outb;
          dst[(((size_t)(bb * Hn + hh)) * Sn + ss) * HDn + dd] = f2bf(v);
        } else if (MODE == 1) {
          const int hh = (col >> 6) & 15, dd = col & 63;
          const int bb = row >> 11, ss = row & 2047;
          outb[(((size_t)(bb * Hn + hh)) * Sn + ss) * HDn + dd] = f2bf(v);
        } else if (MODE == 2) {
          outf[idx] = v + lam * res[idx];
        } else if (MODE == 3) {
          const float t = 0.7978845608028654f * (v + 0.044715f * v * v * v);
          outb[idx] = f2bf(0.5f * v * (1.f + tanhf(t)));
        } else {
          outf[idx] = v + res[idx];
        }
      }
    }
  }
}

// ---------------------------------------------------------------------------
// Linear attention, chunked (chunk=256), fp32 math, head-major layouts.
// q/k/v are [b*H + h][Sn][64] bf16 -> all tile loads contiguous.
// Pass A: per (c, bh): KV_c[64][64] = sum_j k_j (x) v_j ; ksum_c[64]
// ---------------------------------------------------------------------------
__global__ __launch_bounds__(256)
void attn_stats_k(const unsigned short* __restrict__ kh,
                  const unsigned short* __restrict__ vh,
                  float* __restrict__ stats) {
  const int c = blockIdx.x, bh = blockIdx.y;
  const int tid = threadIdx.x;
  __shared__ float ks[64][64];
  __shared__ float vs[64][64];
  const int dm = tid >> 2;          // 0..63 (d index)
  const int g0 = tid & 3;           // f4-group base
  f4 acc[4] = {};
  float ksum = 0.f;
  const size_t base = ((size_t)bh * Sn + (size_t)c * 256) * HDn;

  for (int sub = 0; sub < 4; ++sub) {
    __syncthreads();
    #pragma unroll
    for (int li = tid; li < 512; li += 256) {   // 64 rows x 8 groups of 8 elems
      const int j  = li >> 3;
      const int d8 = (li & 7) << 3;
      const size_t g = base + (size_t)(sub * 64 + j) * HDn + d8;
      f4 a, b;
      load8bf(kh + g, &a, &b);
      *(f4*)&ks[j][d8] = a; *(f4*)&ks[j][d8 + 4] = b;
      load8bf(vh + g, &a, &b);
      *(f4*)&vs[j][d8] = a; *(f4*)&vs[j][d8 + 4] = b;
    }
    __syncthreads();
    for (int j = 0; j < 64; ++j) {
      const float s = ks[j][dm];
      const f4* vrow = (const f4*)vs[j];
      #pragma unroll
      for (int g = 0; g < 4; ++g) acc[g] += s * vrow[g0 * 4 + g];
    }
    // ksum: thread (dm,g0) sums its 16-row slice of column dm
    #pragma unroll
    for (int t = 0; t < 16; ++t) ksum += ks[g0 * 16 + t][dm];
  }
  // reduce ksum over the 4 threads sharing dm (adjacent lanes)
  ksum += __shfl_xor(ksum, 1);
  ksum += __shfl_xor(ksum, 2);

  float* op = stats + ((size_t)bh * NCHUNK + c) * 4160 + dm * 64 + g0 * 16;
  #pragma unroll
  for (int g = 0; g < 4; ++g) *(f4*)(op + g * 4) = acc[g];
  if (g0 == 0) stats[((size_t)bh * NCHUNK + c) * 4160 + 4096 + dm] = ksum;
}

// Pass B: exclusive scan over chunks per (b,h)
__global__ __launch_bounds__(256)
void attn_scan_k(const float* __restrict__ stats, float* __restrict__ prefix) {
  const int bh = blockIdx.x;
  const int tid = threadIdx.x;
  for (int idx = tid; idx < 4160; idx += 256) {
    float r = 0.f;
    for (int c = 0; c < NCHUNK; ++c) {
      prefix[((size_t)bh * NCHUNK + c) * 4160 + idx] = r;
      r += stats[((size_t)bh * NCHUNK + c) * 4160 + idx];
    }
  }
}

// Pass C: per (c, bh): one thread per row, head-major in/out-to-token-major.
__global__ __launch_bounds__(256)
void attn_out_k(const unsigned short* __restrict__ qh,
                const unsigned short* __restrict__ kh,
                const unsigned short* __restrict__ vh,
                const float* __restrict__ prefix,
                unsigned short* __restrict__ ctx) {
  const int c = blockIdx.x, bh = blockIdx.y;
  const int b = bh >> 4, h = bh & 15;
  const int tid = threadIdx.x;
  const int w = tid >> 6;
  const int i = tid;  // row within chunk

  __shared__ float ks[64][64];
  __shared__ float vs[64][64];
  __shared__ float kvp[64 * 64];
  __shared__ float ksp[64];

  const size_t base = ((size_t)bh * Sn + (size_t)c * 256) * HDn;
  const unsigned short* qp = qh + base + (size_t)i * HDn;

  f4 qv[16];
  #pragma unroll
  for (int g = 0; g < 16; ++g) qv[g] = load4bf(qp + g * 4);

  const float* pf = prefix + ((size_t)bh * NCHUNK + c) * 4160;
  for (int idx = tid; idx < 1024; idx += 256)
    ((f4*)kvp)[idx] = ((const f4*)pf)[idx];
  if (tid < 64) ksp[tid] = pf[4096 + tid];
  __syncthreads();

  f4 outv[16];
  #pragma unroll
  for (int g = 0; g < 16; ++g) outv[g] = (f4){0.f, 0.f, 0.f, 0.f};
  float den = 0.f;

  // inter-chunk: out += q @ KV_prefix ; den += q . ksum_prefix
  // (static qv indices -> stays in registers; kv rows broadcast from LDS)
  #pragma unroll
  for (int g = 0; g < 16; ++g) {
    #pragma unroll
    for (int cc = 0; cc < 4; ++cc) {
      const int d = g * 4 + cc;
      const float qd = qv[g][cc];
      den += qd * ksp[d];
      const f4* kvrow = (const f4*)(kvp + d * 64);
      #pragma unroll
      for (int g2 = 0; g2 < 16; ++g2) outv[g2] += qd * kvrow[g2];
    }
  }

  // intra-chunk, causal
  for (int sub = 0; sub < 4; ++sub) {
    __syncthreads();
    #pragma unroll
    for (int li = tid; li < 512; li += 256) {
      const int j  = li >> 3;
      const int d8 = (li & 7) << 3;
      const size_t g = base + (size_t)(sub * 64 + j) * HDn + d8;
      f4 a, bb;
      load8bf(kh + g, &a, &bb);
      *(f4*)&ks[j][d8] = a; *(f4*)&ks[j][d8 + 4] = bb;
      load8bf(vh + g, &a, &bb);
      *(f4*)&vs[j][d8] = a; *(f4*)&vs[j][d8 + 4] = bb;
    }
    __syncthreads();
    if (w >= sub) {
      const int jg0 = sub * 64;
      const bool diag = (sub == w);
      for (int jl = 0; jl < 64; ++jl) {
        const f4* krow = (const f4*)ks[jl];
        f4 sa = (f4){0.f, 0.f, 0.f, 0.f};
        #pragma unroll
        for (int g = 0; g < 16; ++g) sa += qv[g] * krow[g];
        float s = sa[0] + sa[1] + sa[2] + sa[3];
        if (diag && (jg0 + jl) > i) s = 0.f;
        den += s;
        const f4* vrow = (const f4*)vs[jl];
        #pragma unroll
        for (int g = 0; g < 16; ++g) outv[g] += s * vrow[g];
      }
    }
  }

  const float n = 1.f / den;
  // ctx is token-major [b][s][h*64+d] for the O-projection GEMM
  unsigned short* cp = ctx + (((size_t)b * Sn + c * 256 + i) * Dn) + h * HDn;
  #pragma unroll
  for (int g = 0; g < 16; ++g) store4bf(cp + g * 4, outv[g] * n);
}

// ---------------------------------------------------------------------------
extern "C" void kernel_launch(void* const* d_in, const int* in_sizes, int n_in,
                              void* d_out, int out_size, void* d_ws, size_t ws_size,
                              hipStream_t stream) {
  const float* x     = (const float*)d_in[0];
  const float* lambd = (const float*)d_in[1];
  const float* ln_g  = (const float*)d_in[2];
  const float* ln_b  = (const float*)d_in[3];
  const float* Wqk   = (const float*)d_in[4];
  const float* bqk   = (const float*)d_in[5];
  const float* Wv    = (const float*)d_in[6];
  const float* bv    = (const float*)d_in[7];
  const float* Wo    = (const float*)d_in[8];
  const float* bo    = (const float*)d_in[9];
  const float* W1    = (const float*)d_in[10];
  const float* b1    = (const float*)d_in[11];
  const float* W2    = (const float*)d_in[12];
  const float* b2    = (const float*)d_in[13];
  float* out = (float*)d_out;

  char* ws = (char*)d_ws;
  size_t off = 0;
  auto alloc = [&](size_t bytes) -> void* {
    void* p = ws + off;
    off += (bytes + 255) & ~(size_t)255;
    return p;
  };
  unsigned short* wqk_t = (unsigned short*)alloc((size_t)2048 * 1024 * 2);
  unsigned short* wv_t  = (unsigned short*)alloc((size_t)1024 * 1024 * 2);
  unsigned short* wo_t  = (unsigned short*)alloc((size_t)1024 * 1024 * 2);
  unsigned short* w1_t  = (unsigned short*)alloc((size_t)4096 * 1024 * 2);
  unsigned short* w2_t  = (unsigned short*)alloc((size_t)1024 * 4096 * 2);
  unsigned short* xn    = (unsigned short*)alloc((size_t)Mn * Dn * 2);     // also y
  // qh,kh,vh,ctxb: 8 MB each, contiguous 32 MB; all dead before MLP1 -> hb alias
  unsigned short* qh    = (unsigned short*)alloc((size_t)Mn * Dn * 2);
  unsigned short* kh    = (unsigned short*)alloc((size_t)Mn * Dn * 2);
  unsigned short* vh    = (unsigned short*)alloc((size_t)Mn * Dn * 2);
  unsigned short* ctxb  = (unsigned short*)alloc((size_t)Mn * Dn * 2);
  float*          xmid  = (float*)alloc((size_t)Mn * Dn * 4);
  float*          stats = (float*)alloc((size_t)32 * NCHUNK * 4160 * 4);
  float*          prefx = (float*)alloc((size_t)32 * NCHUNK * 4160 * 4);
  unsigned short* hb    = qh;  // alias: 32 MB for MLP hidden

  dim3 tb(32, 8);
  transpose_to_bf16<<<dim3(64, 32),  tb, 0, stream>>>(Wqk, wqk_t, 1024, 2048);
  transpose_to_bf16<<<dim3(32, 32),  tb, 0, stream>>>(Wv,  wv_t,  1024, 1024);
  transpose_to_bf16<<<dim3(32, 32),  tb, 0, stream>>>(Wo,  wo_t,  1024, 1024);
  transpose_to_bf16<<<dim3(128, 32), tb, 0, stream>>>(W1,  w1_t,  1024, 4096);
  transpose_to_bf16<<<dim3(32, 128), tb, 0, stream>>>(W2,  w2_t,  4096, 1024);

  ln_k<<<Mn, 256, 0, stream>>>(x, ln_g, ln_b, xn);

  gemm_bt<0><<<dim3(32, 16), 256, 0, stream>>>(xn, wqk_t, Mn, 2048, 1024,
                                               bqk, nullptr, nullptr, nullptr, qh, kh);
  gemm_bt<1><<<dim3(32, 8), 256, 0, stream>>>(xn, wv_t, Mn, 1024, 1024,
                                              bv, nullptr, nullptr, nullptr, vh, nullptr);

  attn_stats_k<<<dim3(NCHUNK, 32), 256, 0, stream>>>(kh, vh, stats);
  attn_scan_k<<<32, 256, 0, stream>>>(stats, prefx);
  attn_out_k<<<dim3(NCHUNK, 32), 256, 0, stream>>>(qh, kh, vh, prefx, ctxb);

  gemm_bt<2><<<dim3(32, 8), 256, 0, stream>>>(ctxb, wo_t, Mn, 1024, 1024,
                                              bo, x, lambd, xmid, nullptr, nullptr);

  ln_k<<<Mn, 256, 0, stream>>>(xmid, ln_g, ln_b, xn);  // xn now holds y

  gemm_bt<3><<<dim3(32, 32), 256, 0, stream>>>(xn, w1_t, Mn, 4096, 1024,
                                               b1, nullptr, nullptr, nullptr, hb, nullptr);
  gemm_bt<4><<<dim3(32, 8), 256, 0, stream>>>(hb, w2_t, Mn, 1024, 4096,
                                              b2, xmid, nullptr, out, nullptr, nullptr);
}

// Round 3
// 556.247 us; speedup vs baseline: 2.1196x; 2.1196x over previous
//
#include <hip/hip_runtime.h>
#include <math.h>

// Problem constants
#define Bn 2
#define Sn 2048
#define Dn 1024
#define Hn 16
#define HDn 64
#define MLPn 4096
#define Mn 4096  // Bn*Sn tokens
#define NCHUNK 8 // Sn/256

typedef float f4 __attribute__((ext_vector_type(4)));
typedef short bfrag __attribute__((ext_vector_type(8)));     // 8 bf16 for MFMA
typedef unsigned int u32x2 __attribute__((ext_vector_type(2)));
typedef unsigned int u32x4 __attribute__((ext_vector_type(4)));
typedef unsigned short u16x4 __attribute__((ext_vector_type(4)));

__device__ __forceinline__ unsigned short f2bf(float f) {
  unsigned u = __float_as_uint(f);
  u += 0x7fffu + ((u >> 16) & 1u);   // RNE
  return (unsigned short)(u >> 16);
}
__device__ __forceinline__ float bf2f(unsigned short u) {
  return __uint_as_float(((unsigned)u) << 16);
}
__device__ __forceinline__ f4 load4bf(const unsigned short* p) {
  u32x2 u = *(const u32x2*)p;
  f4 r;
  r[0] = __uint_as_float(u[0] << 16);
  r[1] = __uint_as_float(u[0] & 0xffff0000u);
  r[2] = __uint_as_float(u[1] << 16);
  r[3] = __uint_as_float(u[1] & 0xffff0000u);
  return r;
}
// 8 bf16 (16B, coalescing sweet spot) -> two f4
__device__ __forceinline__ void load8bf(const unsigned short* p, f4* a, f4* b) {
  u32x4 u = *(const u32x4*)p;
  (*a)[0] = __uint_as_float(u[0] << 16);
  (*a)[1] = __uint_as_float(u[0] & 0xffff0000u);
  (*a)[2] = __uint_as_float(u[1] << 16);
  (*a)[3] = __uint_as_float(u[1] & 0xffff0000u);
  (*b)[0] = __uint_as_float(u[2] << 16);
  (*b)[1] = __uint_as_float(u[2] & 0xffff0000u);
  (*b)[2] = __uint_as_float(u[3] << 16);
  (*b)[3] = __uint_as_float(u[3] & 0xffff0000u);
}
__device__ __forceinline__ void store4bf(unsigned short* p, f4 v) {
  u16x4 o;
  o[0] = f2bf(v[0]); o[1] = f2bf(v[1]); o[2] = f2bf(v[2]); o[3] = f2bf(v[3]);
  *(u16x4*)p = o;
}

#define GLOAD16(gp, lp) __builtin_amdgcn_global_load_lds( \
    (const __attribute__((address_space(1))) void*)(gp),  \
    (__attribute__((address_space(3))) void*)(lp), 16, 0, 0)

// ---------------------------------------------------------------------------
// Weight transpose + fp32->bf16: in [K][N] fp32  ->  out [N][K] bf16
// ---------------------------------------------------------------------------
__global__ void transpose_to_bf16(const float* __restrict__ in,
                                  unsigned short* __restrict__ out,
                                  int K, int N) {
  __shared__ float tile[32][33];
  const int n0 = blockIdx.x * 32;
  const int k0 = blockIdx.y * 32;
  const int tx = threadIdx.x, ty = threadIdx.y;  // (32,8)
  #pragma unroll
  for (int i = 0; i < 32; i += 8)
    tile[ty + i][tx] = in[(size_t)(k0 + ty + i) * N + n0 + tx];
  __syncthreads();
  #pragma unroll
  for (int i = 0; i < 32; i += 8)
    out[(size_t)(n0 + ty + i) * K + k0 + tx] = f2bf(tile[tx][ty + i]);
}

// ---------------------------------------------------------------------------
// LayerNorm over D=1024, fp32 in -> bf16 out. One block per row.
// ---------------------------------------------------------------------------
__global__ __launch_bounds__(256)
void ln_k(const float* __restrict__ x, const float* __restrict__ g,
          const float* __restrict__ bta, unsigned short* __restrict__ out) {
  const int row = blockIdx.x;
  const int tid = threadIdx.x;
  const float* xr = x + (size_t)row * Dn;
  f4 v = ((const f4*)xr)[tid];
  float s  = v[0] + v[1] + v[2] + v[3];
  float s2 = v[0]*v[0] + v[1]*v[1] + v[2]*v[2] + v[3]*v[3];
  #pragma unroll
  for (int off = 32; off > 0; off >>= 1) {
    s  += __shfl_down(s, off);
    s2 += __shfl_down(s2, off);
  }
  __shared__ float red[8];
  if ((tid & 63) == 0) { red[tid >> 6] = s; red[4 + (tid >> 6)] = s2; }
  __syncthreads();
  const float mean = (red[0] + red[1] + red[2] + red[3]) * (1.f / Dn);
  const float var  = (red[4] + red[5] + red[6] + red[7]) * (1.f / Dn) - mean * mean;
  const float inv  = rsqrtf(var + 1e-5f);
  f4 gv = ((const f4*)g)[tid];
  f4 bv = ((const f4*)bta)[tid];
  u16x4 o;
  o[0] = f2bf((v[0] - mean) * inv * gv[0] + bv[0]);
  o[1] = f2bf((v[1] - mean) * inv * gv[1] + bv[1]);
  o[2] = f2bf((v[2] - mean) * inv * gv[2] + bv[2]);
  o[3] = f2bf((v[3] - mean) * inv * gv[3] + bv[3]);
  ((u16x4*)(out + (size_t)row * Dn))[tid] = o;
}

// ---------------------------------------------------------------------------
// bf16 MFMA GEMM, m97 structure: C[M][N] = A[M][K] * Bt[N][K]^T (+ epilogue)
// 128x128 tile, BK=32, 4 waves (2x2), 4x4 16x16 fragments per wave.
// MODE 0: bf16 = elu(acc+b)+1, scatter head-major -> q (outb) / k (outb2)
// MODE 1: bf16 = acc+b, scatter head-major -> v (outb)
// MODE 2: f32  = acc+b+lambd*res           (attn_out + skip -> xmid)
// MODE 3: bf16 = gelu_tanh(acc+b)          (mlp hidden)
// MODE 4: f32  = acc+b+res                 (final)
// ---------------------------------------------------------------------------
template<int MODE>
__global__ __launch_bounds__(256)
void gemm_bt(const unsigned short* __restrict__ A,
             const unsigned short* __restrict__ Bt,
             int Mdim, int Ndim, int Kdim,
             const float* __restrict__ bias,
             const float* __restrict__ res,
             const float* __restrict__ lambd,
             float* __restrict__ outf,
             unsigned short* __restrict__ outb,
             unsigned short* __restrict__ outb2) {
  __shared__ unsigned short As[128 * 32];
  __shared__ unsigned short Bs[128 * 32];
  const int tid  = threadIdx.x;
  const int lane = tid & 63;
  const int wid  = tid >> 6;
  const int wr   = wid >> 1, wc = wid & 1;
  const int bm = blockIdx.x, bn = blockIdx.y;

  f4 acc[4][4] = {};

  const int lrow = lane >> 2;        // 0..15
  const int lcol = (lane & 3) * 8;   // element col within BK
  const unsigned short* Ag = A + (size_t)(bm * 128 + lrow) * Kdim + lcol;
  const unsigned short* Bg = Bt + (size_t)(bn * 128 + lrow) * Kdim + lcol;

  const int arow = wr * 64 + (lane & 15);
  const int brow = wc * 64 + (lane & 15);
  const int koff = (lane >> 4) * 8;

  for (int kt = 0; kt < Kdim; kt += 32) {
    __syncthreads();
    #pragma unroll
    for (int i = 0; i < 2; ++i) {
      const int rbase = (wid * 2 + i) * 16;
      GLOAD16(Ag + (size_t)rbase * Kdim + kt, As + rbase * 32);
      GLOAD16(Bg + (size_t)rbase * Kdim + kt, Bs + rbase * 32);
    }
    __syncthreads();

    bfrag af[4], bfr[4];
    #pragma unroll
    for (int mi = 0; mi < 4; ++mi)
      af[mi] = *(const bfrag*)(As + (arow + mi * 16) * 32 + koff);
    #pragma unroll
    for (int ni = 0; ni < 4; ++ni)
      bfr[ni] = *(const bfrag*)(Bs + (brow + ni * 16) * 32 + koff);
    #pragma unroll
    for (int mi = 0; mi < 4; ++mi)
      #pragma unroll
      for (int ni = 0; ni < 4; ++ni)
        acc[mi][ni] = __builtin_amdgcn_mfma_f32_16x16x32_bf16(
            af[mi], bfr[ni], acc[mi][ni], 0, 0, 0);
  }

  // epilogue
  const int r0 = bm * 128 + wr * 64 + ((lane >> 4) << 2);
  const int c0 = bn * 128 + wc * 64 + (lane & 15);
  const float lam = (MODE == 2) ? lambd[0] : 0.f;
  #pragma unroll
  for (int mi = 0; mi < 4; ++mi) {
    #pragma unroll
    for (int ni = 0; ni < 4; ++ni) {
      const int col = c0 + ni * 16;
      const float bcol = bias[col];
      #pragma unroll
      for (int r = 0; r < 4; ++r) {
        const int row = r0 + mi * 16 + r;
        const size_t idx = (size_t)row * Ndim + col;
        float v = acc[mi][ni][r] + bcol;
        if (MODE == 0) {
          v = (v > 0.f) ? (v + 1.f) : __expf(v);   // elu+1
          const int part = col >> 10, hh = (col >> 6) & 15, dd = col & 63;
          const int bb = row >> 11, ss = row & 2047;
          unsigned short* dst = part ? outb2 : outb;
          dst[(((size_t)(bb * Hn + hh)) * Sn + ss) * HDn + dd] = f2bf(v);
        } else if (MODE == 1) {
          const int hh = (col >> 6) & 15, dd = col & 63;
          const int bb = row >> 11, ss = row & 2047;
          outb[(((size_t)(bb * Hn + hh)) * Sn + ss) * HDn + dd] = f2bf(v);
        } else if (MODE == 2) {
          outf[idx] = v + lam * res[idx];
        } else if (MODE == 3) {
          const float t = 0.7978845608028654f * (v + 0.044715f * v * v * v);
          outb[idx] = f2bf(0.5f * v * (1.f + tanhf(t)));
        } else {
          outf[idx] = v + res[idx];
        }
      }
    }
  }
}

// ---------------------------------------------------------------------------
// Linear attention, chunked (chunk=256), fp32 math, head-major layouts.
// q/k/v are [b*H + h][Sn][64] bf16 -> all tile loads contiguous.
// Pass A: per (c, bh): KV_c[64][64] = sum_j k_j (x) v_j ; ksum_c[64]
// ---------------------------------------------------------------------------
__global__ __launch_bounds__(256)
void attn_stats_k(const unsigned short* __restrict__ kh,
                  const unsigned short* __restrict__ vh,
                  float* __restrict__ stats) {
  const int c = blockIdx.x, bh = blockIdx.y;
  const int tid = threadIdx.x;
  __shared__ float ks[64][64];
  __shared__ float vs[64][64];
  const int dm = tid >> 2;          // 0..63 (d index)
  const int g0 = tid & 3;           // f4-group base
  f4 acc[4] = {};
  float ksum = 0.f;
  const size_t base = ((size_t)bh * Sn + (size_t)c * 256) * HDn;

  for (int sub = 0; sub < 4; ++sub) {
    __syncthreads();
    #pragma unroll
    for (int li = tid; li < 512; li += 256) {   // 64 rows x 8 groups of 8 elems
      const int j  = li >> 3;
      const int d8 = (li & 7) << 3;
      const size_t g = base + (size_t)(sub * 64 + j) * HDn + d8;
      f4 a, b;
      load8bf(kh + g, &a, &b);
      *(f4*)&ks[j][d8] = a; *(f4*)&ks[j][d8 + 4] = b;
      load8bf(vh + g, &a, &b);
      *(f4*)&vs[j][d8] = a; *(f4*)&vs[j][d8 + 4] = b;
    }
    __syncthreads();
    for (int j = 0; j < 64; ++j) {
      const float s = ks[j][dm];
      const f4* vrow = (const f4*)vs[j];
      #pragma unroll
      for (int g = 0; g < 4; ++g) acc[g] += s * vrow[g0 * 4 + g];
    }
    // ksum: thread (dm,g0) sums its 16-row slice of column dm
    #pragma unroll
    for (int t = 0; t < 16; ++t) ksum += ks[g0 * 16 + t][dm];
  }
  // reduce ksum over the 4 threads sharing dm (adjacent lanes)
  ksum += __shfl_xor(ksum, 1);
  ksum += __shfl_xor(ksum, 2);

  float* op = stats + ((size_t)bh * NCHUNK + c) * 4160 + dm * 64 + g0 * 16;
  #pragma unroll
  for (int g = 0; g < 4; ++g) *(f4*)(op + g * 4) = acc[g];
  if (g0 == 0) stats[((size_t)bh * NCHUNK + c) * 4160 + 4096 + dm] = ksum;
}

// Pass B: exclusive scan over chunks per (b,h)
__global__ __launch_bounds__(256)
void attn_scan_k(const float* __restrict__ stats, float* __restrict__ prefix) {
  const int bh = blockIdx.x;
  const int tid = threadIdx.x;
  for (int idx = tid; idx < 4160; idx += 256) {
    float r = 0.f;
    for (int c = 0; c < NCHUNK; ++c) {
      prefix[((size_t)bh * NCHUNK + c) * 4160 + idx] = r;
      r += stats[((size_t)bh * NCHUNK + c) * 4160 + idx];
    }
  }
}

// Pass C: per (c, bh): one thread per row, head-major in/out-to-token-major.
// NOTE: inter-chunk loop deliberately uses a RUNTIME d index with q re-read
// from global (L1-hot). The fully-unrolled static-qv version spilled to
// scratch (round 2: 1.48 GB HBM traffic/dispatch, 733 us).
__global__ __launch_bounds__(256)
void attn_out_k(const unsigned short* __restrict__ qh,
                const unsigned short* __restrict__ kh,
                const unsigned short* __restrict__ vh,
                const float* __restrict__ prefix,
                unsigned short* __restrict__ ctx) {
  const int c = blockIdx.x, bh = blockIdx.y;
  const int b = bh >> 4, h = bh & 15;
  const int tid = threadIdx.x;
  const int w = tid >> 6;
  const int i = tid;  // row within chunk

  __shared__ float ks[64][64];
  __shared__ float vs[64][64];
  __shared__ float kvp[64 * 64];
  __shared__ float ksp[64];

  const size_t base = ((size_t)bh * Sn + (size_t)c * 256) * HDn;
  const unsigned short* qp = qh + base + (size_t)i * HDn;

  f4 qv[16];
  #pragma unroll
  for (int g = 0; g < 16; ++g) qv[g] = load4bf(qp + g * 4);

  const float* pf = prefix + ((size_t)bh * NCHUNK + c) * 4160;
  for (int idx = tid; idx < 1024; idx += 256)
    ((f4*)kvp)[idx] = ((const f4*)pf)[idx];
  if (tid < 64) ksp[tid] = pf[4096 + tid];
  __syncthreads();

  f4 outv[16];
  #pragma unroll
  for (int g = 0; g < 16; ++g) outv[g] = (f4){0.f, 0.f, 0.f, 0.f};
  float den = 0.f;

  // inter-chunk: out += q @ KV_prefix ; den += q . ksum_prefix
  // (runtime d, q scalar re-read from global -> low register pressure)
  for (int d = 0; d < 64; ++d) {
    const float qd = bf2f(qp[d]);
    den += qd * ksp[d];
    const f4* kvrow = (const f4*)(kvp + d * 64);
    #pragma unroll
    for (int g2 = 0; g2 < 16; ++g2) outv[g2] += qd * kvrow[g2];
  }

  // intra-chunk, causal
  for (int sub = 0; sub < 4; ++sub) {
    __syncthreads();
    #pragma unroll
    for (int li = tid; li < 512; li += 256) {
      const int j  = li >> 3;
      const int d8 = (li & 7) << 3;
      const size_t g = base + (size_t)(sub * 64 + j) * HDn + d8;
      f4 a, bb;
      load8bf(kh + g, &a, &bb);
      *(f4*)&ks[j][d8] = a; *(f4*)&ks[j][d8 + 4] = bb;
      load8bf(vh + g, &a, &bb);
      *(f4*)&vs[j][d8] = a; *(f4*)&vs[j][d8 + 4] = bb;
    }
    __syncthreads();
    if (w >= sub) {
      const int jg0 = sub * 64;
      const bool diag = (sub == w);
      for (int jl = 0; jl < 64; ++jl) {
        const f4* krow = (const f4*)ks[jl];
        f4 sa = (f4){0.f, 0.f, 0.f, 0.f};
        #pragma unroll
        for (int g = 0; g < 16; ++g) sa += qv[g] * krow[g];
        float s = sa[0] + sa[1] + sa[2] + sa[3];
        if (diag && (jg0 + jl) > i) s = 0.f;
        den += s;
        const f4* vrow = (const f4*)vs[jl];
        #pragma unroll
        for (int g = 0; g < 16; ++g) outv[g] += s * vrow[g];
      }
    }
  }

  const float n = 1.f / den;
  // ctx is token-major [b][s][h*64+d] for the O-projection GEMM
  unsigned short* cp = ctx + (((size_t)b * Sn + c * 256 + i) * Dn) + h * HDn;
  #pragma unroll
  for (int g = 0; g < 16; ++g) store4bf(cp + g * 4, outv[g] * n);
}

// ---------------------------------------------------------------------------
extern "C" void kernel_launch(void* const* d_in, const int* in_sizes, int n_in,
                              void* d_out, int out_size, void* d_ws, size_t ws_size,
                              hipStream_t stream) {
  const float* x     = (const float*)d_in[0];
  const float* lambd = (const float*)d_in[1];
  const float* ln_g  = (const float*)d_in[2];
  const float* ln_b  = (const float*)d_in[3];
  const float* Wqk   = (const float*)d_in[4];
  const float* bqk   = (const float*)d_in[5];
  const float* Wv    = (const float*)d_in[6];
  const float* bv    = (const float*)d_in[7];
  const float* Wo    = (const float*)d_in[8];
  const float* bo    = (const float*)d_in[9];
  const float* W1    = (const float*)d_in[10];
  const float* b1    = (const float*)d_in[11];
  const float* W2    = (const float*)d_in[12];
  const float* b2    = (const float*)d_in[13];
  float* out = (float*)d_out;

  char* ws = (char*)d_ws;
  size_t off = 0;
  auto alloc = [&](size_t bytes) -> void* {
    void* p = ws + off;
    off += (bytes + 255) & ~(size_t)255;
    return p;
  };
  unsigned short* wqk_t = (unsigned short*)alloc((size_t)2048 * 1024 * 2);
  unsigned short* wv_t  = (unsigned short*)alloc((size_t)1024 * 1024 * 2);
  unsigned short* wo_t  = (unsigned short*)alloc((size_t)1024 * 1024 * 2);
  unsigned short* w1_t  = (unsigned short*)alloc((size_t)4096 * 1024 * 2);
  unsigned short* w2_t  = (unsigned short*)alloc((size_t)1024 * 4096 * 2);
  unsigned short* xn    = (unsigned short*)alloc((size_t)Mn * Dn * 2);     // also y
  // qh,kh,vh,ctxb: 8 MB each, contiguous 32 MB; all dead before MLP1 -> hb alias
  unsigned short* qh    = (unsigned short*)alloc((size_t)Mn * Dn * 2);
  unsigned short* kh    = (unsigned short*)alloc((size_t)Mn * Dn * 2);
  unsigned short* vh    = (unsigned short*)alloc((size_t)Mn * Dn * 2);
  unsigned short* ctxb  = (unsigned short*)alloc((size_t)Mn * Dn * 2);
  float*          xmid  = (float*)alloc((size_t)Mn * Dn * 4);
  float*          stats = (float*)alloc((size_t)32 * NCHUNK * 4160 * 4);
  float*          prefx = (float*)alloc((size_t)32 * NCHUNK * 4160 * 4);
  unsigned short* hb    = qh;  // alias: 32 MB for MLP hidden

  dim3 tb(32, 8);
  transpose_to_bf16<<<dim3(64, 32),  tb, 0, stream>>>(Wqk, wqk_t, 1024, 2048);
  transpose_to_bf16<<<dim3(32, 32),  tb, 0, stream>>>(Wv,  wv_t,  1024, 1024);
  transpose_to_bf16<<<dim3(32, 32),  tb, 0, stream>>>(Wo,  wo_t,  1024, 1024);
  transpose_to_bf16<<<dim3(128, 32), tb, 0, stream>>>(W1,  w1_t,  1024, 4096);
  transpose_to_bf16<<<dim3(32, 128), tb, 0, stream>>>(W2,  w2_t,  4096, 1024);

  ln_k<<<Mn, 256, 0, stream>>>(x, ln_g, ln_b, xn);

  gemm_bt<0><<<dim3(32, 16), 256, 0, stream>>>(xn, wqk_t, Mn, 2048, 1024,
                                               bqk, nullptr, nullptr, nullptr, qh, kh);
  gemm_bt<1><<<dim3(32, 8), 256, 0, stream>>>(xn, wv_t, Mn, 1024, 1024,
                                              bv, nullptr, nullptr, nullptr, vh, nullptr);

  attn_stats_k<<<dim3(NCHUNK, 32), 256, 0, stream>>>(kh, vh, stats);
  attn_scan_k<<<32, 256, 0, stream>>>(stats, prefx);
  attn_out_k<<<dim3(NCHUNK, 32), 256, 0, stream>>>(qh, kh, vh, prefx, ctxb);

  gemm_bt<2><<<dim3(32, 8), 256, 0, stream>>>(ctxb, wo_t, Mn, 1024, 1024,
                                              bo, x, lambd, xmid, nullptr, nullptr);

  ln_k<<<Mn, 256, 0, stream>>>(xmid, ln_g, ln_b, xn);  // xn now holds y

  gemm_bt<3><<<dim3(32, 32), 256, 0, stream>>>(xn, w1_t, Mn, 4096, 1024,
                                               b1, nullptr, nullptr, nullptr, hb, nullptr);
  gemm_bt<4><<<dim3(32, 8), 256, 0, stream>>>(hb, w2_t, Mn, 1024, 4096,
                                              b2, xmid, nullptr, out, nullptr, nullptr);
}

// Round 6
// 451.210 us; speedup vs baseline: 2.6131x; 1.2328x over previous
//
#include <hip/hip_runtime.h>
#include <math.h>

// Problem constants
#define Bn 2
#define Sn 2048
#define Dn 1024
#define Hn 16
#define HDn 64
#define MLPn 4096
#define Mn 4096   // Bn*Sn tokens
#define NCHUNK 32 // Sn/64: 64-row chunks for linear-attention state scan

typedef float f4 __attribute__((ext_vector_type(4)));
typedef short bfrag __attribute__((ext_vector_type(8)));     // 8 bf16 for MFMA
typedef unsigned int u32x2 __attribute__((ext_vector_type(2)));
typedef unsigned int u32x4 __attribute__((ext_vector_type(4)));
typedef unsigned short u16x4 __attribute__((ext_vector_type(4)));

__device__ __forceinline__ unsigned short f2bf(float f) {
  unsigned u = __float_as_uint(f);
  u += 0x7fffu + ((u >> 16) & 1u);   // RNE
  return (unsigned short)(u >> 16);
}
__device__ __forceinline__ float bf2f(unsigned short u) {
  return __uint_as_float(((unsigned)u) << 16);
}
__device__ __forceinline__ f4 load4bf(const unsigned short* p) {
  u32x2 u = *(const u32x2*)p;
  f4 r;
  r[0] = __uint_as_float(u[0] << 16);
  r[1] = __uint_as_float(u[0] & 0xffff0000u);
  r[2] = __uint_as_float(u[1] << 16);
  r[3] = __uint_as_float(u[1] & 0xffff0000u);
  return r;
}
// 8 bf16 (16B, coalescing sweet spot) -> two f4
__device__ __forceinline__ void load8bf(const unsigned short* p, f4* a, f4* b) {
  u32x4 u = *(const u32x4*)p;
  (*a)[0] = __uint_as_float(u[0] << 16);
  (*a)[1] = __uint_as_float(u[0] & 0xffff0000u);
  (*a)[2] = __uint_as_float(u[1] << 16);
  (*a)[3] = __uint_as_float(u[1] & 0xffff0000u);
  (*b)[0] = __uint_as_float(u[2] << 16);
  (*b)[1] = __uint_as_float(u[2] & 0xffff0000u);
  (*b)[2] = __uint_as_float(u[3] << 16);
  (*b)[3] = __uint_as_float(u[3] & 0xffff0000u);
}
__device__ __forceinline__ void store4bf(unsigned short* p, f4 v) {
  u16x4 o;
  o[0] = f2bf(v[0]); o[1] = f2bf(v[1]); o[2] = f2bf(v[2]); o[3] = f2bf(v[3]);
  *(u16x4*)p = o;
}

#define GLOAD16(gp, lp) __builtin_amdgcn_global_load_lds( \
    (const __attribute__((address_space(1))) void*)(gp),  \
    (__attribute__((address_space(3))) void*)(lp), 16, 0, 0)

// ---------------------------------------------------------------------------
// Weight transpose + fp32->bf16: in [K][N] fp32  ->  out [N][K] bf16
// ---------------------------------------------------------------------------
__global__ void transpose_to_bf16(const float* __restrict__ in,
                                  unsigned short* __restrict__ out,
                                  int K, int N) {
  __shared__ float tile[32][33];
  const int n0 = blockIdx.x * 32;
  const int k0 = blockIdx.y * 32;
  const int tx = threadIdx.x, ty = threadIdx.y;  // (32,8)
  #pragma unroll
  for (int i = 0; i < 32; i += 8)
    tile[ty + i][tx] = in[(size_t)(k0 + ty + i) * N + n0 + tx];
  __syncthreads();
  #pragma unroll
  for (int i = 0; i < 32; i += 8)
    out[(size_t)(n0 + ty + i) * K + k0 + tx] = f2bf(tile[tx][ty + i]);
}

// ---------------------------------------------------------------------------
// LayerNorm over D=1024, fp32 in -> bf16 out. One block per row.
// ---------------------------------------------------------------------------
__global__ __launch_bounds__(256)
void ln_k(const float* __restrict__ x, const float* __restrict__ g,
          const float* __restrict__ bta, unsigned short* __restrict__ out) {
  const int row = blockIdx.x;
  const int tid = threadIdx.x;
  const float* xr = x + (size_t)row * Dn;
  f4 v = ((const f4*)xr)[tid];
  float s  = v[0] + v[1] + v[2] + v[3];
  float s2 = v[0]*v[0] + v[1]*v[1] + v[2]*v[2] + v[3]*v[3];
  #pragma unroll
  for (int off = 32; off > 0; off >>= 1) {
    s  += __shfl_down(s, off);
    s2 += __shfl_down(s2, off);
  }
  __shared__ float red[8];
  if ((tid & 63) == 0) { red[tid >> 6] = s; red[4 + (tid >> 6)] = s2; }
  __syncthreads();
  const float mean = (red[0] + red[1] + red[2] + red[3]) * (1.f / Dn);
  const float var  = (red[4] + red[5] + red[6] + red[7]) * (1.f / Dn) - mean * mean;
  const float inv  = rsqrtf(var + 1e-5f);
  f4 gv = ((const f4*)g)[tid];
  f4 bv = ((const f4*)bta)[tid];
  u16x4 o;
  o[0] = f2bf((v[0] - mean) * inv * gv[0] + bv[0]);
  o[1] = f2bf((v[1] - mean) * inv * gv[1] + bv[1]);
  o[2] = f2bf((v[2] - mean) * inv * gv[2] + bv[2]);
  o[3] = f2bf((v[3] - mean) * inv * gv[3] + bv[3]);
  ((u16x4*)(out + (size_t)row * Dn))[tid] = o;
}

// ---------------------------------------------------------------------------
// bf16 MFMA GEMM, m97 structure: C[M][N] = A[M][K] * Bt[N][K]^T (+ epilogue)
// 128x128 tile, BK=32, 4 waves (2x2), 4x4 16x16 fragments per wave.
// MODE 0: bf16 = elu(acc+b)+1, scatter head-major -> q (outb) / k (outb2)
// MODE 1: bf16 = acc+b, scatter head-major -> v (outb)
// MODE 2: f32  = acc+b+lambd*res           (attn_out + skip -> xmid)
// MODE 3: bf16 = gelu_tanh(acc+b)          (mlp hidden)
// MODE 4: f32  = acc+b+res                 (final)
// ---------------------------------------------------------------------------
template<int MODE>
__global__ __launch_bounds__(256)
void gemm_bt(const unsigned short* __restrict__ A,
             const unsigned short* __restrict__ Bt,
             int Mdim, int Ndim, int Kdim,
             const float* __restrict__ bias,
             const float* __restrict__ res,
             const float* __restrict__ lambd,
             float* __restrict__ outf,
             unsigned short* __restrict__ outb,
             unsigned short* __restrict__ outb2) {
  __shared__ unsigned short As[128 * 32];
  __shared__ unsigned short Bs[128 * 32];
  const int tid  = threadIdx.x;
  const int lane = tid & 63;
  const int wid  = tid >> 6;
  const int wr   = wid >> 1, wc = wid & 1;
  const int bm = blockIdx.x, bn = blockIdx.y;

  f4 acc[4][4] = {};

  const int lrow = lane >> 2;        // 0..15
  const int lcol = (lane & 3) * 8;   // element col within BK
  const unsigned short* Ag = A + (size_t)(bm * 128 + lrow) * Kdim + lcol;
  const unsigned short* Bg = Bt + (size_t)(bn * 128 + lrow) * Kdim + lcol;

  const int arow = wr * 64 + (lane & 15);
  const int brow = wc * 64 + (lane & 15);
  const int koff = (lane >> 4) * 8;

  for (int kt = 0; kt < Kdim; kt += 32) {
    __syncthreads();
    #pragma unroll
    for (int i = 0; i < 2; ++i) {
      const int rbase = (wid * 2 + i) * 16;
      GLOAD16(Ag + (size_t)rbase * Kdim + kt, As + rbase * 32);
      GLOAD16(Bg + (size_t)rbase * Kdim + kt, Bs + rbase * 32);
    }
    __syncthreads();

    bfrag af[4], bfr[4];
    #pragma unroll
    for (int mi = 0; mi < 4; ++mi)
      af[mi] = *(const bfrag*)(As + (arow + mi * 16) * 32 + koff);
    #pragma unroll
    for (int ni = 0; ni < 4; ++ni)
      bfr[ni] = *(const bfrag*)(Bs + (brow + ni * 16) * 32 + koff);
    #pragma unroll
    for (int mi = 0; mi < 4; ++mi)
      #pragma unroll
      for (int ni = 0; ni < 4; ++ni)
        acc[mi][ni] = __builtin_amdgcn_mfma_f32_16x16x32_bf16(
            af[mi], bfr[ni], acc[mi][ni], 0, 0, 0);
  }

  // epilogue
  const int r0 = bm * 128 + wr * 64 + ((lane >> 4) << 2);
  const int c0 = bn * 128 + wc * 64 + (lane & 15);
  const float lam = (MODE == 2) ? lambd[0] : 0.f;
  #pragma unroll
  for (int mi = 0; mi < 4; ++mi) {
    #pragma unroll
    for (int ni = 0; ni < 4; ++ni) {
      const int col = c0 + ni * 16;
      const float bcol = bias[col];
      #pragma unroll
      for (int r = 0; r < 4; ++r) {
        const int row = r0 + mi * 16 + r;
        const size_t idx = (size_t)row * Ndim + col;
        float v = acc[mi][ni][r] + bcol;
        if (MODE == 0) {
          v = (v > 0.f) ? (v + 1.f) : __expf(v);   // elu+1
          const int part = col >> 10, hh = (col >> 6) & 15, dd = col & 63;
          const int bb = row >> 11, ss = row & 2047;
          unsigned short* dst = part ? outb2 : outb;
          dst[(((size_t)(bb * Hn + hh)) * Sn + ss) * HDn + dd] = f2bf(v);
        } else if (MODE == 1) {
          const int hh = (col >> 6) & 15, dd = col & 63;
          const int bb = row >> 11, ss = row & 2047;
          outb[(((size_t)(bb * Hn + hh)) * Sn + ss) * HDn + dd] = f2bf(v);
        } else if (MODE == 2) {
          outf[idx] = v + lam * res[idx];
        } else if (MODE == 3) {
          const float t = 0.7978845608028654f * (v + 0.044715f * v * v * v);
          outb[idx] = f2bf(0.5f * v * (1.f + tanhf(t)));
        } else {
          outf[idx] = v + res[idx];
        }
      }
    }
  }
}

// ---------------------------------------------------------------------------
// Linear attention, 64-row chunks, head-major layouts.
// q/k/v: [b*H + h][Sn][64] bf16. State scan at 64 granularity -> intra part
// of each block is only its own 64x64 causal tile.
// Pass A: per (g, bh): KV_g[64][64] = sum_j k_j (x) v_j ; ksum_g[64]
// ---------------------------------------------------------------------------
__global__ __launch_bounds__(256)
void attn_stats_k(const unsigned short* __restrict__ kh,
                  const unsigned short* __restrict__ vh,
                  float* __restrict__ stats) {
  const int g = blockIdx.x, bh = blockIdx.y;
  const int tid = threadIdx.x;
  __shared__ unsigned short ks[64 * 64];
  __shared__ unsigned short vs[64 * 64];
  const size_t base = ((size_t)bh * Sn + (size_t)g * 64) * HDn;
  #pragma unroll
  for (int r = 0; r < 2; ++r) {
    GLOAD16(kh + base + (size_t)(r * 256 + tid) * 8, ks + (r * 256 + tid) * 8);
    GLOAD16(vh + base + (size_t)(r * 256 + tid) * 8, vs + (r * 256 + tid) * 8);
  }
  __syncthreads();

  const int dm = tid >> 2, quad = tid & 3;
  f4 acc[4] = {};
  float ksum = 0.f;
  for (int j = 0; j < 64; ++j) {
    const float kd = bf2f(ks[j * 64 + dm]);
    ksum += kd;
    #pragma unroll
    for (int gg = 0; gg < 4; ++gg)
      acc[gg] += kd * load4bf(vs + j * 64 + quad * 16 + gg * 4);
  }
  float* op = stats + ((size_t)bh * NCHUNK + g) * 4160 + dm * 64 + quad * 16;
  #pragma unroll
  for (int gg = 0; gg < 4; ++gg) *(f4*)(op + gg * 4) = acc[gg];
  if (quad == 0) stats[((size_t)bh * NCHUNK + g) * 4160 + 4096 + dm] = ksum;
}

// Pass B: exclusive scan over 32 chunks per (b,h). grid (32, 17)
__global__ __launch_bounds__(256)
void attn_scan_k(const float* __restrict__ stats, float* __restrict__ prefix) {
  const int bh = blockIdx.x;
  const int idx = blockIdx.y * 256 + threadIdx.x;
  if (idx >= 4160) return;
  float r = 0.f;
  for (int c = 0; c < NCHUNK; ++c) {
    prefix[((size_t)bh * NCHUNK + c) * 4160 + idx] = r;
    r += stats[((size_t)bh * NCHUNK + c) * 4160 + idx];
  }
}

// Pass C: per (g, bh): 64 rows, 4 lanes per row (lane quad owns 16 of 64 dims).
// inter: O += q @ KV_prefix (KV bf16 in LDS, ksum fp32); intra: own causal tile.
__global__ __launch_bounds__(256)
void attn_out_k(const unsigned short* __restrict__ qh,
                const unsigned short* __restrict__ kh,
                const unsigned short* __restrict__ vh,
                const float* __restrict__ prefix,
                unsigned short* __restrict__ ctx) {
  const int g = blockIdx.x, bh = blockIdx.y;
  const int b = bh >> 4, h = bh & 15;
  const int tid = threadIdx.x;
  const int i = tid >> 2, quad = tid & 3;

  __shared__ unsigned short ks[64 * 64];   // [j][d]
  __shared__ unsigned short vs[64 * 64];   // [j][d]
  __shared__ unsigned short qt[64 * 64];   // [d][i] transposed
  __shared__ unsigned short kvp[64 * 64];  // [d][t] bf16
  __shared__ float ksp[64];

  const size_t base = ((size_t)bh * Sn + (size_t)g * 64) * HDn;
  #pragma unroll
  for (int r = 0; r < 2; ++r) {
    GLOAD16(kh + base + (size_t)(r * 256 + tid) * 8, ks + (r * 256 + tid) * 8);
    GLOAD16(vh + base + (size_t)(r * 256 + tid) * 8, vs + (r * 256 + tid) * 8);
  }
  // q transposed into LDS: qt[d][j] = q[j][d]
  #pragma unroll
  for (int r = 0; r < 2; ++r) {
    const int li = r * 256 + tid;
    const int j = li >> 3, d8 = (li & 7) << 3;
    u32x4 u = *(const u32x4*)(qh + base + (size_t)j * HDn + d8);
    const unsigned short* pv = (const unsigned short*)&u;
    #pragma unroll
    for (int t = 0; t < 8; ++t) qt[(d8 + t) * 64 + j] = pv[t];
  }
  // KV prefix fp32 -> bf16 LDS; ksum stays fp32
  const float* pf = prefix + ((size_t)bh * NCHUNK + g) * 4160;
  #pragma unroll
  for (int t = 0; t < 4; ++t) {
    f4 v = *(const f4*)(pf + tid * 16 + t * 4);
    u16x4 o;
    o[0] = f2bf(v[0]); o[1] = f2bf(v[1]); o[2] = f2bf(v[2]); o[3] = f2bf(v[3]);
    *(u16x4*)(kvp + tid * 16 + t * 4) = o;
  }
  if (tid < 64) ksp[tid] = pf[4096 + tid];
  __syncthreads();

  // q fragment for intra dot: this row's 16 dims (quad range)
  f4 qr[4];
  {
    const unsigned short* qp = qh + base + (size_t)i * HDn + quad * 16;
    load8bf(qp, &qr[0], &qr[1]);
    load8bf(qp + 8, &qr[2], &qr[3]);
  }

  f4 outv[4] = {};
  float den = 0.f;

  // inter-chunk: O[i][t] += sum_d q[i][d] * KV[d][t] ; den += q . ksum
  for (int d = 0; d < 64; ++d) {
    const float qd = bf2f(qt[d * 64 + i]);
    den += qd * ksp[d];
    #pragma unroll
    for (int gg = 0; gg < 4; ++gg)
      outv[gg] += qd * load4bf(kvp + d * 64 + quad * 16 + gg * 4);
  }

  // intra-chunk causal: 4-lane team computes s via shfl-reduced partial dots
  for (int j = 0; j < 64; ++j) {
    f4 p = qr[0] * load4bf(ks + j * 64 + quad * 16);
    p += qr[1] * load4bf(ks + j * 64 + quad * 16 + 4);
    p += qr[2] * load4bf(ks + j * 64 + quad * 16 + 8);
    p += qr[3] * load4bf(ks + j * 64 + quad * 16 + 12);
    float s = p[0] + p[1] + p[2] + p[3];
    s += __shfl_xor(s, 1);
    s += __shfl_xor(s, 2);
    if (j > i) s = 0.f;
    den += s;
    #pragma unroll
    for (int gg = 0; gg < 4; ++gg)
      outv[gg] += s * load4bf(vs + j * 64 + quad * 16 + gg * 4);
  }

  const float n = 1.f / den;
  // ctx token-major [b][s][h*64+d] for the O-projection GEMM
  unsigned short* cp = ctx + ((size_t)(b * Sn + g * 64 + i) * Dn) + h * HDn + quad * 16;
  #pragma unroll
  for (int gg = 0; gg < 4; ++gg) store4bf(cp + gg * 4, outv[gg] * n);
}

// ---------------------------------------------------------------------------
extern "C" void kernel_launch(void* const* d_in, const int* in_sizes, int n_in,
                              void* d_out, int out_size, void* d_ws, size_t ws_size,
                              hipStream_t stream) {
  const float* x     = (const float*)d_in[0];
  const float* lambd = (const float*)d_in[1];
  const float* ln_g  = (const float*)d_in[2];
  const float* ln_b  = (const float*)d_in[3];
  const float* Wqk   = (const float*)d_in[4];
  const float* bqk   = (const float*)d_in[5];
  const float* Wv    = (const float*)d_in[6];
  const float* bv    = (const float*)d_in[7];
  const float* Wo    = (const float*)d_in[8];
  const float* bo    = (const float*)d_in[9];
  const float* W1    = (const float*)d_in[10];
  const float* b1    = (const float*)d_in[11];
  const float* W2    = (const float*)d_in[12];
  const float* b2    = (const float*)d_in[13];
  float* out = (float*)d_out;

  char* ws = (char*)d_ws;
  size_t off = 0;
  auto alloc = [&](size_t bytes) -> void* {
    void* p = ws + off;
    off += (bytes + 255) & ~(size_t)255;
    return p;
  };
  unsigned short* wqk_t = (unsigned short*)alloc((size_t)2048 * 1024 * 2);
  unsigned short* wv_t  = (unsigned short*)alloc((size_t)1024 * 1024 * 2);
  unsigned short* wo_t  = (unsigned short*)alloc((size_t)1024 * 1024 * 2);
  unsigned short* w1_t  = (unsigned short*)alloc((size_t)4096 * 1024 * 2);
  unsigned short* w2_t  = (unsigned short*)alloc((size_t)1024 * 4096 * 2);
  unsigned short* xn    = (unsigned short*)alloc((size_t)Mn * Dn * 2);     // also y
  // qh,kh,vh,ctxb: 8 MB each; all dead before MLP1 -> hb alias
  unsigned short* qh    = (unsigned short*)alloc((size_t)Mn * Dn * 2);
  unsigned short* kh    = (unsigned short*)alloc((size_t)Mn * Dn * 2);
  unsigned short* vh    = (unsigned short*)alloc((size_t)Mn * Dn * 2);
  unsigned short* ctxb  = (unsigned short*)alloc((size_t)Mn * Dn * 2);
  float*          xmid  = (float*)alloc((size_t)Mn * Dn * 4);
  float*          stats = (float*)alloc((size_t)32 * NCHUNK * 4160 * 4);
  float*          prefx = (float*)alloc((size_t)32 * NCHUNK * 4160 * 4);
  unsigned short* hb    = qh;  // alias: 32 MB for MLP hidden

  dim3 tb(32, 8);
  transpose_to_bf16<<<dim3(64, 32),  tb, 0, stream>>>(Wqk, wqk_t, 1024, 2048);
  transpose_to_bf16<<<dim3(32, 32),  tb, 0, stream>>>(Wv,  wv_t,  1024, 1024);
  transpose_to_bf16<<<dim3(32, 32),  tb, 0, stream>>>(Wo,  wo_t,  1024, 1024);
  transpose_to_bf16<<<dim3(128, 32), tb, 0, stream>>>(W1,  w1_t,  1024, 4096);
  transpose_to_bf16<<<dim3(32, 128), tb, 0, stream>>>(W2,  w2_t,  4096, 1024);

  ln_k<<<Mn, 256, 0, stream>>>(x, ln_g, ln_b, xn);

  gemm_bt<0><<<dim3(32, 16), 256, 0, stream>>>(xn, wqk_t, Mn, 2048, 1024,
                                               bqk, nullptr, nullptr, nullptr, qh, kh);
  gemm_bt<1><<<dim3(32, 8), 256, 0, stream>>>(xn, wv_t, Mn, 1024, 1024,
                                              bv, nullptr, nullptr, nullptr, vh, nullptr);

  attn_stats_k<<<dim3(NCHUNK, 32), 256, 0, stream>>>(kh, vh, stats);
  attn_scan_k<<<dim3(32, 17), 256, 0, stream>>>(stats, prefx);
  attn_out_k<<<dim3(NCHUNK, 32), 256, 0, stream>>>(qh, kh, vh, prefx, ctxb);

  gemm_bt<2><<<dim3(32, 8), 256, 0, stream>>>(ctxb, wo_t, Mn, 1024, 1024,
                                              bo, x, lambd, xmid, nullptr, nullptr);

  ln_k<<<Mn, 256, 0, stream>>>(xmid, ln_g, ln_b, xn);  // xn now holds y

  gemm_bt<3><<<dim3(32, 32), 256, 0, stream>>>(xn, w1_t, Mn, 4096, 1024,
                                               b1, nullptr, nullptr, nullptr, hb, nullptr);
  gemm_bt<4><<<dim3(32, 8), 256, 0, stream>>>(hb, w2_t, Mn, 1024, 4096,
                                              b2, xmid, nullptr, out, nullptr, nullptr);
}

// Round 9
// 436.261 us; speedup vs baseline: 2.7026x; 1.0343x over previous
//
#include <hip/hip_runtime.h>
#include <math.h>

// Problem constants
#define Bn 2
#define Sn 2048
#define Dn 1024
#define Hn 16
#define HDn 64
#define MLPn 4096
#define Mn 4096   // Bn*Sn tokens
#define NCHUNK 32 // Sn/64: 64-row chunks for linear-attention state scan

typedef float f4 __attribute__((ext_vector_type(4)));
typedef short bfrag __attribute__((ext_vector_type(8)));     // 8 bf16 for MFMA
typedef unsigned int u32x2 __attribute__((ext_vector_type(2)));
typedef unsigned int u32x4 __attribute__((ext_vector_type(4)));
typedef unsigned short u16x4 __attribute__((ext_vector_type(4)));

__device__ __forceinline__ unsigned short f2bf(float f) {
  unsigned u = __float_as_uint(f);
  u += 0x7fffu + ((u >> 16) & 1u);   // RNE
  return (unsigned short)(u >> 16);
}
__device__ __forceinline__ float bf2f(unsigned short u) {
  return __uint_as_float(((unsigned)u) << 16);
}
__device__ __forceinline__ f4 load4bf(const unsigned short* p) {
  u32x2 u = *(const u32x2*)p;
  f4 r;
  r[0] = __uint_as_float(u[0] << 16);
  r[1] = __uint_as_float(u[0] & 0xffff0000u);
  r[2] = __uint_as_float(u[1] << 16);
  r[3] = __uint_as_float(u[1] & 0xffff0000u);
  return r;
}
// 8 bf16 (16B, coalescing sweet spot) -> two f4
__device__ __forceinline__ void load8bf(const unsigned short* p, f4* a, f4* b) {
  u32x4 u = *(const u32x4*)p;
  (*a)[0] = __uint_as_float(u[0] << 16);
  (*a)[1] = __uint_as_float(u[0] & 0xffff0000u);
  (*a)[2] = __uint_as_float(u[1] << 16);
  (*a)[3] = __uint_as_float(u[1] & 0xffff0000u);
  (*b)[0] = __uint_as_float(u[2] << 16);
  (*b)[1] = __uint_as_float(u[2] & 0xffff0000u);
  (*b)[2] = __uint_as_float(u[3] << 16);
  (*b)[3] = __uint_as_float(u[3] & 0xffff0000u);
}
__device__ __forceinline__ void store4bf(unsigned short* p, f4 v) {
  u16x4 o;
  o[0] = f2bf(v[0]); o[1] = f2bf(v[1]); o[2] = f2bf(v[2]); o[3] = f2bf(v[3]);
  *(u16x4*)p = o;
}

#define GLOAD16(gp, lp) __builtin_amdgcn_global_load_lds( \
    (const __attribute__((address_space(1))) void*)(gp),  \
    (__attribute__((address_space(3))) void*)(lp), 16, 0, 0)

// ---------------------------------------------------------------------------
// Weight transpose + fp32->bf16: in [K][N] fp32  ->  out [N][K] bf16
// ---------------------------------------------------------------------------
__global__ void transpose_to_bf16(const float* __restrict__ in,
                                  unsigned short* __restrict__ out,
                                  int K, int N) {
  __shared__ float tile[32][33];
  const int n0 = blockIdx.x * 32;
  const int k0 = blockIdx.y * 32;
  const int tx = threadIdx.x, ty = threadIdx.y;  // (32,8)
  #pragma unroll
  for (int i = 0; i < 32; i += 8)
    tile[ty + i][tx] = in[(size_t)(k0 + ty + i) * N + n0 + tx];
  __syncthreads();
  #pragma unroll
  for (int i = 0; i < 32; i += 8)
    out[(size_t)(n0 + ty + i) * K + k0 + tx] = f2bf(tile[tx][ty + i]);
}

// ---------------------------------------------------------------------------
// LayerNorm over D=1024, fp32 in -> bf16 out. One block per row.
// ---------------------------------------------------------------------------
__global__ __launch_bounds__(256)
void ln_k(const float* __restrict__ x, const float* __restrict__ g,
          const float* __restrict__ bta, unsigned short* __restrict__ out) {
  const int row = blockIdx.x;
  const int tid = threadIdx.x;
  const float* xr = x + (size_t)row * Dn;
  f4 v = ((const f4*)xr)[tid];
  float s  = v[0] + v[1] + v[2] + v[3];
  float s2 = v[0]*v[0] + v[1]*v[1] + v[2]*v[2] + v[3]*v[3];
  #pragma unroll
  for (int off = 32; off > 0; off >>= 1) {
    s  += __shfl_down(s, off);
    s2 += __shfl_down(s2, off);
  }
  __shared__ float red[8];
  if ((tid & 63) == 0) { red[tid >> 6] = s; red[4 + (tid >> 6)] = s2; }
  __syncthreads();
  const float mean = (red[0] + red[1] + red[2] + red[3]) * (1.f / Dn);
  const float var  = (red[4] + red[5] + red[6] + red[7]) * (1.f / Dn) - mean * mean;
  const float inv  = rsqrtf(var + 1e-5f);
  f4 gv = ((const f4*)g)[tid];
  f4 bv = ((const f4*)bta)[tid];
  u16x4 o;
  o[0] = f2bf((v[0] - mean) * inv * gv[0] + bv[0]);
  o[1] = f2bf((v[1] - mean) * inv * gv[1] + bv[1]);
  o[2] = f2bf((v[2] - mean) * inv * gv[2] + bv[2]);
  o[3] = f2bf((v[3] - mean) * inv * gv[3] + bv[3]);
  ((u16x4*)(out + (size_t)row * Dn))[tid] = o;
}

// ---------------------------------------------------------------------------
// bf16 MFMA GEMM: C[M][N] = A[M][K] * Bt[N][K]^T (+ epilogue)
// 128x128 tile, BK=32, 4 waves (2x2), 4x4 16x16 fragments per wave.
// Double-buffered LDS (T3 minimum 2-phase): issue next tile's
// global_load_lds BEFORE computing current tile; ONE barrier per K-step.
// Rescues the 1-block/CU shapes (V/O/MLP2) where no other block hides the
// vmcnt(0) drain (round 6: MLP2 368 TF, MfmaUtil 14%).
// MODE 0: bf16 = elu(acc+b)+1, scatter head-major -> q (outb) / k (outb2)
// MODE 1: bf16 = acc+b, scatter head-major -> v (outb)
// MODE 2: f32  = acc+b+lambd*res           (attn_out + skip -> xmid)
// MODE 3: bf16 = gelu_tanh(acc+b)          (mlp hidden)
// MODE 4: f32  = acc+b+res                 (final)
// ---------------------------------------------------------------------------
template<int MODE>
__global__ __launch_bounds__(256)
void gemm_bt(const unsigned short* __restrict__ A,
             const unsigned short* __restrict__ Bt,
             int Mdim, int Ndim, int Kdim,
             const float* __restrict__ bias,
             const float* __restrict__ res,
             const float* __restrict__ lambd,
             float* __restrict__ outf,
             unsigned short* __restrict__ outb,
             unsigned short* __restrict__ outb2) {
  __shared__ unsigned short As[2 * 128 * 32];
  __shared__ unsigned short Bs[2 * 128 * 32];
  const int tid  = threadIdx.x;
  const int lane = tid & 63;
  const int wid  = tid >> 6;
  const int wr   = wid >> 1, wc = wid & 1;
  const int bm = blockIdx.x, bn = blockIdx.y;

  f4 acc[4][4] = {};

  const int lrow = lane >> 2;        // 0..15
  const int lcol = (lane & 3) * 8;   // element col within BK
  const unsigned short* Ag = A + (size_t)(bm * 128 + lrow) * Kdim + lcol;
  const unsigned short* Bg = Bt + (size_t)(bn * 128 + lrow) * Kdim + lcol;

  const int arow = wr * 64 + (lane & 15);
  const int brow = wc * 64 + (lane & 15);
  const int koff = (lane >> 4) * 8;

  // stage tile (kt) into buffer buf. LDS dest wave-uniform; HW adds lane*16B.
  auto stage = [&](int buf, int kt) {
    #pragma unroll
    for (int i2 = 0; i2 < 2; ++i2) {
      const int rbase = (wid * 2 + i2) * 16;
      GLOAD16(Ag + (size_t)rbase * Kdim + kt, As + buf * (128 * 32) + rbase * 32);
      GLOAD16(Bg + (size_t)rbase * Kdim + kt, Bs + buf * (128 * 32) + rbase * 32);
    }
  };

  const int nt = Kdim >> 5;
  stage(0, 0);
  __syncthreads();          // drain vmcnt -> buffer 0 ready
  int cur = 0;

  for (int t = 0; t < nt; ++t) {
    if (t + 1 < nt) stage(cur ^ 1, (t + 1) << 5);   // prefetch next tile

    const unsigned short* Ab = As + cur * (128 * 32);
    const unsigned short* Bb = Bs + cur * (128 * 32);
    bfrag af[4], bfr[4];
    #pragma unroll
    for (int mi = 0; mi < 4; ++mi)
      af[mi] = *(const bfrag*)(Ab + (arow + mi * 16) * 32 + koff);
    #pragma unroll
    for (int ni = 0; ni < 4; ++ni)
      bfr[ni] = *(const bfrag*)(Bb + (brow + ni * 16) * 32 + koff);
    #pragma unroll
    for (int mi = 0; mi < 4; ++mi)
      #pragma unroll
      for (int ni = 0; ni < 4; ++ni)
        acc[mi][ni] = __builtin_amdgcn_mfma_f32_16x16x32_bf16(
            af[mi], bfr[ni], acc[mi][ni], 0, 0, 0);

    __syncthreads();        // waits prefetch loads (vmcnt0) + read-done on cur
    cur ^= 1;
  }

  // epilogue
  const int r0 = bm * 128 + wr * 64 + ((lane >> 4) << 2);
  const int c0 = bn * 128 + wc * 64 + (lane & 15);
  const float lam = (MODE == 2) ? lambd[0] : 0.f;
  #pragma unroll
  for (int mi = 0; mi < 4; ++mi) {
    #pragma unroll
    for (int ni = 0; ni < 4; ++ni) {
      const int col = c0 + ni * 16;
      const float bcol = bias[col];
      #pragma unroll
      for (int r = 0; r < 4; ++r) {
        const int row = r0 + mi * 16 + r;
        const size_t idx = (size_t)row * Ndim + col;
        float v = acc[mi][ni][r] + bcol;
        if (MODE == 0) {
          v = (v > 0.f) ? (v + 1.f) : __expf(v);   // elu+1
          const int part = col >> 10, hh = (col >> 6) & 15, dd = col & 63;
          const int bb = row >> 11, ss = row & 2047;
          unsigned short* dst = part ? outb2 : outb;
          dst[(((size_t)(bb * Hn + hh)) * Sn + ss) * HDn + dd] = f2bf(v);
        } else if (MODE == 1) {
          const int hh = (col >> 6) & 15, dd = col & 63;
          const int bb = row >> 11, ss = row & 2047;
          outb[(((size_t)(bb * Hn + hh)) * Sn + ss) * HDn + dd] = f2bf(v);
        } else if (MODE == 2) {
          outf[idx] = v + lam * res[idx];
        } else if (MODE == 3) {
          const float t = 0.7978845608028654f * (v + 0.044715f * v * v * v);
          outb[idx] = f2bf(0.5f * v * (1.f + tanhf(t)));
        } else {
          outf[idx] = v + res[idx];
        }
      }
    }
  }
}

// ---------------------------------------------------------------------------
// Linear attention, 64-row chunks, head-major layouts.
// q/k/v: [b*H + h][Sn][64] bf16. State scan at 64 granularity -> intra part
// of each block is only its own 64x64 causal tile.
// Pass A: per (g, bh): KV_g[64][64] = sum_j k_j (x) v_j ; ksum_g[64]
// ---------------------------------------------------------------------------
__global__ __launch_bounds__(256)
void attn_stats_k(const unsigned short* __restrict__ kh,
                  const unsigned short* __restrict__ vh,
                  float* __restrict__ stats) {
  const int g = blockIdx.x, bh = blockIdx.y;
  const int tid = threadIdx.x;
  __shared__ unsigned short ks[64 * 64];
  __shared__ unsigned short vs[64 * 64];
  const size_t base = ((size_t)bh * Sn + (size_t)g * 64) * HDn;
  #pragma unroll
  for (int r = 0; r < 2; ++r) {
    GLOAD16(kh + base + (size_t)(r * 256 + tid) * 8, ks + (r * 256 + tid) * 8);
    GLOAD16(vh + base + (size_t)(r * 256 + tid) * 8, vs + (r * 256 + tid) * 8);
  }
  __syncthreads();

  const int dm = tid >> 2, quad = tid & 3;
  f4 acc[4] = {};
  float ksum = 0.f;
  for (int j = 0; j < 64; ++j) {
    const float kd = bf2f(ks[j * 64 + dm]);
    ksum += kd;
    #pragma unroll
    for (int gg = 0; gg < 4; ++gg)
      acc[gg] += kd * load4bf(vs + j * 64 + quad * 16 + gg * 4);
  }
  float* op = stats + ((size_t)bh * NCHUNK + g) * 4160 + dm * 64 + quad * 16;
  #pragma unroll
  for (int gg = 0; gg < 4; ++gg) *(f4*)(op + gg * 4) = acc[gg];
  if (quad == 0) stats[((size_t)bh * NCHUNK + g) * 4160 + 4096 + dm] = ksum;
}

// Pass B: exclusive scan over 32 chunks per (b,h). grid (32, 17)
__global__ __launch_bounds__(256)
void attn_scan_k(const float* __restrict__ stats, float* __restrict__ prefix) {
  const int bh = blockIdx.x;
  const int idx = blockIdx.y * 256 + threadIdx.x;
  if (idx >= 4160) return;
  float r = 0.f;
  for (int c = 0; c < NCHUNK; ++c) {
    prefix[((size_t)bh * NCHUNK + c) * 4160 + idx] = r;
    r += stats[((size_t)bh * NCHUNK + c) * 4160 + idx];
  }
}

// Pass C: per (g, bh): 64 rows, 4 lanes per row (lane quad owns 16 of 64 dims).
// inter: O += q @ KV_prefix (KV bf16 in LDS, ksum fp32); intra: own causal tile.
__global__ __launch_bounds__(256)
void attn_out_k(const unsigned short* __restrict__ qh,
                const unsigned short* __restrict__ kh,
                const unsigned short* __restrict__ vh,
                const float* __restrict__ prefix,
                unsigned short* __restrict__ ctx) {
  const int g = blockIdx.x, bh = blockIdx.y;
  const int b = bh >> 4, h = bh & 15;
  const int tid = threadIdx.x;
  const int i = tid >> 2, quad = tid & 3;

  __shared__ unsigned short ks[64 * 64];   // [j][d]
  __shared__ unsigned short vs[64 * 64];   // [j][d]
  __shared__ unsigned short qt[64 * 64];   // [d][i] transposed
  __shared__ unsigned short kvp[64 * 64];  // [d][t] bf16
  __shared__ float ksp[64];

  const size_t base = ((size_t)bh * Sn + (size_t)g * 64) * HDn;
  #pragma unroll
  for (int r = 0; r < 2; ++r) {
    GLOAD16(kh + base + (size_t)(r * 256 + tid) * 8, ks + (r * 256 + tid) * 8);
    GLOAD16(vh + base + (size_t)(r * 256 + tid) * 8, vs + (r * 256 + tid) * 8);
  }
  // q transposed into LDS: qt[d][j] = q[j][d]
  #pragma unroll
  for (int r = 0; r < 2; ++r) {
    const int li = r * 256 + tid;
    const int j = li >> 3, d8 = (li & 7) << 3;
    u32x4 u = *(const u32x4*)(qh + base + (size_t)j * HDn + d8);
    const unsigned short* pv = (const unsigned short*)&u;
    #pragma unroll
    for (int t = 0; t < 8; ++t) qt[(d8 + t) * 64 + j] = pv[t];
  }
  // KV prefix fp32 -> bf16 LDS; ksum stays fp32
  const float* pf = prefix + ((size_t)bh * NCHUNK + g) * 4160;
  #pragma unroll
  for (int t = 0; t < 4; ++t) {
    f4 v = *(const f4*)(pf + tid * 16 + t * 4);
    u16x4 o;
    o[0] = f2bf(v[0]); o[1] = f2bf(v[1]); o[2] = f2bf(v[2]); o[3] = f2bf(v[3]);
    *(u16x4*)(kvp + tid * 16 + t * 4) = o;
  }
  if (tid < 64) ksp[tid] = pf[4096 + tid];
  __syncthreads();

  // q fragment for intra dot: this row's 16 dims (quad range)
  f4 qr[4];
  {
    const unsigned short* qp = qh + base + (size_t)i * HDn + quad * 16;
    load8bf(qp, &qr[0], &qr[1]);
    load8bf(qp + 8, &qr[2], &qr[3]);
  }

  f4 outv[4] = {};
  float den = 0.f;

  // inter-chunk: O[i][t] += sum_d q[i][d] * KV[d][t] ; den += q . ksum
  for (int d = 0; d < 64; ++d) {
    const float qd = bf2f(qt[d * 64 + i]);
    den += qd * ksp[d];
    #pragma unroll
    for (int gg = 0; gg < 4; ++gg)
      outv[gg] += qd * load4bf(kvp + d * 64 + quad * 16 + gg * 4);
  }

  // intra-chunk causal: 4-lane team computes s via shfl-reduced partial dots
  for (int j = 0; j < 64; ++j) {
    f4 p = qr[0] * load4bf(ks + j * 64 + quad * 16);
    p += qr[1] * load4bf(ks + j * 64 + quad * 16 + 4);
    p += qr[2] * load4bf(ks + j * 64 + quad * 16 + 8);
    p += qr[3] * load4bf(ks + j * 64 + quad * 16 + 12);
    float s = p[0] + p[1] + p[2] + p[3];
    s += __shfl_xor(s, 1);
    s += __shfl_xor(s, 2);
    if (j > i) s = 0.f;
    den += s;
    #pragma unroll
    for (int gg = 0; gg < 4; ++gg)
      outv[gg] += s * load4bf(vs + j * 64 + quad * 16 + gg * 4);
  }

  const float n = 1.f / den;
  // ctx token-major [b][s][h*64+d] for the O-projection GEMM
  unsigned short* cp = ctx + ((size_t)(b * Sn + g * 64 + i) * Dn) + h * HDn + quad * 16;
  #pragma unroll
  for (int gg = 0; gg < 4; ++gg) store4bf(cp + gg * 4, outv[gg] * n);
}

// ---------------------------------------------------------------------------
extern "C" void kernel_launch(void* const* d_in, const int* in_sizes, int n_in,
                              void* d_out, int out_size, void* d_ws, size_t ws_size,
                              hipStream_t stream) {
  const float* x     = (const float*)d_in[0];
  const float* lambd = (const float*)d_in[1];
  const float* ln_g  = (const float*)d_in[2];
  const float* ln_b  = (const float*)d_in[3];
  const float* Wqk   = (const float*)d_in[4];
  const float* bqk   = (const float*)d_in[5];
  const float* Wv    = (const float*)d_in[6];
  const float* bv    = (const float*)d_in[7];
  const float* Wo    = (const float*)d_in[8];
  const float* bo    = (const float*)d_in[9];
  const float* W1    = (const float*)d_in[10];
  const float* b1    = (const float*)d_in[11];
  const float* W2    = (const float*)d_in[12];
  const float* b2    = (const float*)d_in[13];
  float* out = (float*)d_out;

  char* ws = (char*)d_ws;
  size_t off = 0;
  auto alloc = [&](size_t bytes) -> void* {
    void* p = ws + off;
    off += (bytes + 255) & ~(size_t)255;
    return p;
  };
  unsigned short* wqk_t = (unsigned short*)alloc((size_t)2048 * 1024 * 2);
  unsigned short* wv_t  = (unsigned short*)alloc((size_t)1024 * 1024 * 2);
  unsigned short* wo_t  = (unsigned short*)alloc((size_t)1024 * 1024 * 2);
  unsigned short* w1_t  = (unsigned short*)alloc((size_t)4096 * 1024 * 2);
  unsigned short* w2_t  = (unsigned short*)alloc((size_t)1024 * 4096 * 2);
  unsigned short* xn    = (unsigned short*)alloc((size_t)Mn * Dn * 2);     // also y
  // qh,kh,vh,ctxb: 8 MB each; all dead before MLP1 -> hb alias
  unsigned short* qh    = (unsigned short*)alloc((size_t)Mn * Dn * 2);
  unsigned short* kh    = (unsigned short*)alloc((size_t)Mn * Dn * 2);
  unsigned short* vh    = (unsigned short*)alloc((size_t)Mn * Dn * 2);
  unsigned short* ctxb  = (unsigned short*)alloc((size_t)Mn * Dn * 2);
  float*          xmid  = (float*)alloc((size_t)Mn * Dn * 4);
  float*          stats = (float*)alloc((size_t)32 * NCHUNK * 4160 * 4);
  float*          prefx = (float*)alloc((size_t)32 * NCHUNK * 4160 * 4);
  unsigned short* hb    = qh;  // alias: 32 MB for MLP hidden

  dim3 tb(32, 8);
  transpose_to_bf16<<<dim3(64, 32),  tb, 0, stream>>>(Wqk, wqk_t, 1024, 2048);
  transpose_to_bf16<<<dim3(32, 32),  tb, 0, stream>>>(Wv,  wv_t,  1024, 1024);
  transpose_to_bf16<<<dim3(32, 32),  tb, 0, stream>>>(Wo,  wo_t,  1024, 1024);
  transpose_to_bf16<<<dim3(128, 32), tb, 0, stream>>>(W1,  w1_t,  1024, 4096);
  transpose_to_bf16<<<dim3(32, 128), tb, 0, stream>>>(W2,  w2_t,  4096, 1024);

  ln_k<<<Mn, 256, 0, stream>>>(x, ln_g, ln_b, xn);

  gemm_bt<0><<<dim3(32, 16), 256, 0, stream>>>(xn, wqk_t, Mn, 2048, 1024,
                                               bqk, nullptr, nullptr, nullptr, qh, kh);
  gemm_bt<1><<<dim3(32, 8), 256, 0, stream>>>(xn, wv_t, Mn, 1024, 1024,
                                              bv, nullptr, nullptr, nullptr, vh, nullptr);

  attn_stats_k<<<dim3(NCHUNK, 32), 256, 0, stream>>>(kh, vh, stats);
  attn_scan_k<<<dim3(32, 17), 256, 0, stream>>>(stats, prefx);
  attn_out_k<<<dim3(NCHUNK, 32), 256, 0, stream>>>(qh, kh, vh, prefx, ctxb);

  gemm_bt<2><<<dim3(32, 8), 256, 0, stream>>>(ctxb, wo_t, Mn, 1024, 1024,
                                              bo, x, lambd, xmid, nullptr, nullptr);

  ln_k<<<Mn, 256, 0, stream>>>(xmid, ln_g, ln_b, xn);  // xn now holds y

  gemm_bt<3><<<dim3(32, 32), 256, 0, stream>>>(xn, w1_t, Mn, 4096, 1024,
                                               b1, nullptr, nullptr, nullptr, hb, nullptr);
  gemm_bt<4><<<dim3(32, 8), 256, 0, stream>>>(hb, w2_t, Mn, 1024, 4096,
                                              b2, xmid, nullptr, out, nullptr, nullptr);
}